// Round 1
// baseline (73.104 us; speedup 1.0000x reference)
//
#include <hip/hip_runtime.h>

// Sizes (fixed by the problem)
//   B=512 batches, MBS=32768 samples, F=512 taps, CD=16 cond dims.
// y[b,n] = sum_{t<512} h[b,t] * x[b,n-t]  (linear conv, zero history)

typedef float f32x16 __attribute__((ext_vector_type(16)));
typedef __bf16 bf16x8 __attribute__((ext_vector_type(8)));

__device__ __forceinline__ unsigned short f2bf(float f) {
    unsigned int u = __float_as_uint(f);
    u += 0x7FFFu + ((u >> 16) & 1u);   // round-to-nearest-even
    return (unsigned short)(u >> 16);
}

// ---------------- K0: convert + transpose weights to bf16 ----------------
// WgluT[j][k] = Wglu[k][j]  (j<1024, k<512);  WfT[j][k] = Wf[k][j] (j,k<512)
__global__ __launch_bounds__(256) void k0_convert(
    const float* __restrict__ Wglu, const float* __restrict__ Wf,
    unsigned short* __restrict__ WgluT, unsigned short* __restrict__ WfT) {
    int id = blockIdx.x * 256 + threadIdx.x;            // grid = 3072*256 = 786432
    if (id < 1024 * 512) {
        int j = id >> 9, k = id & 511;
        WgluT[id] = f2bf(Wglu[k * 1024 + j]);
    } else {
        int id2 = id - 1024 * 512;
        int j = id2 >> 9, k = id2 & 511;
        WfT[id2] = f2bf(Wf[k * 512 + j]);
    }
}

// ---------------- K1: Dense16 -> PReLU -> FiLM (fp32) -> bf16 ----------------
__global__ __launch_bounds__(256) void k1_film(
    const float* __restrict__ c, const float* __restrict__ W0,
    const float* __restrict__ b0, const float* __restrict__ alpha,
    const float* __restrict__ Wg, const float* __restrict__ bg,
    const float* __restrict__ Wb, const float* __restrict__ bb,
    unsigned short* __restrict__ cfilm) {
    int id = blockIdx.x * 256 + threadIdx.x;            // grid = 1024 -> 512*512
    int b = id >> 9, f = id & 511;
    const float* cb = c + b * 16;
    float d0 = 0.f, dg = 0.f, db = 0.f;
#pragma unroll
    for (int i = 0; i < 16; ++i) {
        float cv = cb[i];
        d0 += cv * W0[i * 512 + f];
        dg += cv * Wg[i * 512 + f];
        db += cv * Wb[i * 512 + f];
    }
    float pre = d0 + b0[f];
    float pr = pre >= 0.f ? pre : alpha[f] * pre;
    float v = pr * (dg + bg[f]) + (db + bb[f]);
    cfilm[id] = f2bf(v);
}

// ---------------- K2: GLU GEMM (MFMA), fused a*sigmoid(gate) ----------------
// wave computes D tiles [32 batches x 32 cols] for a-cols and gate-cols.
__global__ __launch_bounds__(256) void k2_glu(
    const unsigned short* __restrict__ cfilm, const unsigned short* __restrict__ WgluT,
    const float* __restrict__ bglu, unsigned short* __restrict__ cglu) {
    int wid = (blockIdx.x * 256 + threadIdx.x) >> 6;    // [0,256): 16 m-tiles x 16 col-pairs
    int l = threadIdx.x & 63;
    int tm = wid >> 4, tn = wid & 15;
    int row = tm * 32 + (l & 31);
    int col = tn * 32 + (l & 31);
    int kh = 8 * (l >> 5);
    f32x16 accA, accG;
#pragma unroll
    for (int i = 0; i < 16; ++i) { accA[i] = 0.f; accG[i] = 0.f; }
    const unsigned short* ap = cfilm + row * 512 + kh;
    const unsigned short* bap = WgluT + col * 512 + kh;
    const unsigned short* bgp = WgluT + (512 + col) * 512 + kh;
#pragma unroll 4
    for (int kc = 0; kc < 32; ++kc) {
        bf16x8 a   = *(const bf16x8*)(ap  + kc * 16);
        bf16x8 ba  = *(const bf16x8*)(bap + kc * 16);
        bf16x8 bgt = *(const bf16x8*)(bgp + kc * 16);
        accA = __builtin_amdgcn_mfma_f32_32x32x16_bf16(a, ba,  accA, 0, 0, 0);
        accG = __builtin_amdgcn_mfma_f32_32x32x16_bf16(a, bgt, accG, 0, 0, 0);
    }
    float biasA = bglu[col], biasG = bglu[512 + col];
#pragma unroll
    for (int r = 0; r < 16; ++r) {
        float ga = accA[r] + biasA;
        float gg = accG[r] + biasG;
        float s = 1.f / (1.f + expf(-gg));
        int m = (r & 3) + 8 * (r >> 2) + 4 * (l >> 5);
        cglu[(tm * 32 + m) * 512 + col] = f2bf(ga * s);
    }
}

// ---------------- K3: Dense GEMM (MFMA) + softsign -> filters bf16 ----------------
__global__ __launch_bounds__(256) void k3_filt(
    const unsigned short* __restrict__ cglu, const unsigned short* __restrict__ WfT,
    const float* __restrict__ bfv, unsigned short* __restrict__ hout) {
    int wid = (blockIdx.x * 256 + threadIdx.x) >> 6;    // [0,256): 16 x 16 tiles
    int l = threadIdx.x & 63;
    int tm = wid >> 4, tn = wid & 15;
    int row = tm * 32 + (l & 31);
    int col = tn * 32 + (l & 31);
    int kh = 8 * (l >> 5);
    f32x16 acc;
#pragma unroll
    for (int i = 0; i < 16; ++i) acc[i] = 0.f;
    const unsigned short* ap = cglu + row * 512 + kh;
    const unsigned short* bp = WfT + col * 512 + kh;
#pragma unroll 4
    for (int kc = 0; kc < 32; ++kc) {
        bf16x8 a  = *(const bf16x8*)(ap + kc * 16);
        bf16x8 bv = *(const bf16x8*)(bp + kc * 16);
        acc = __builtin_amdgcn_mfma_f32_32x32x16_bf16(a, bv, acc, 0, 0, 0);
    }
    float bias = bfv[col];
#pragma unroll
    for (int r = 0; r < 16; ++r) {
        float z = acc[r] + bias;
        float h = z / (1.f + fabsf(z));
        int m = (r & 3) + 8 * (r >> 2) + 4 * (l >> 5);
        hout[(tm * 32 + m) * 512 + col] = f2bf(h);
    }
}

// ---------------- K4: MFMA FIR convolution ----------------
// Block: 1 batch x 8192 outputs. 4 waves x 2 tiles(1024 outs) each.
// LDS: x tile (1088 units of 8 bf16, XOR-swizzled)  [0,17408)
//      h row (512 bf16)                             [17408,18432)
//      Toeplitz B-fragments 34 chunks x 64 x 16B    [18432,53248)
__global__ __launch_bounds__(256) void k4_conv(
    const float* __restrict__ x, const unsigned short* __restrict__ hbf,
    float* __restrict__ y) {
    __shared__ __align__(16) unsigned char smem[53248];
    const int tid = threadIdx.x;
    const int b = blockIdx.x >> 2;
    const int n0 = (blockIdx.x & 3) << 13;              // 0,8192,16384,24576

    unsigned short* hs = (unsigned short*)(smem + 17408);
    {   // stage filter row (1 KB)
        const unsigned int* hg = (const unsigned int*)(hbf + (size_t)b * 512);
        ((unsigned int*)hs)[tid] = hg[tid];
    }
    // stage x window [n0-512, n0+8192) as bf16, swizzled at 16B-unit level
    const float* xb = x + (size_t)b * 32768;
#pragma unroll
    for (int it = 0; it < 5; ++it) {
        int u = tid + (it << 8);
        if (u < 1088) {
            int g0 = n0 - 512 + (u << 3);
            unsigned short us[8];
            if (g0 >= 0) {
                const float4* p = (const float4*)(xb + g0);
                float4 v0 = p[0], v1 = p[1];
                us[0] = f2bf(v0.x); us[1] = f2bf(v0.y); us[2] = f2bf(v0.z); us[3] = f2bf(v0.w);
                us[4] = f2bf(v1.x); us[5] = f2bf(v1.y); us[6] = f2bf(v1.z); us[7] = f2bf(v1.w);
            } else {  // only n0==0, u<64: entire unit is pre-history -> zeros
#pragma unroll
                for (int i = 0; i < 8; ++i) us[i] = 0;
            }
            int su = u ^ ((u >> 3) & 7);
            unsigned int q0 = us[0] | ((unsigned int)us[1] << 16);
            unsigned int q1 = us[2] | ((unsigned int)us[3] << 16);
            unsigned int q2 = us[4] | ((unsigned int)us[5] << 16);
            unsigned int q3 = us[6] | ((unsigned int)us[7] << 16);
            *(uint4*)(smem + (su << 4)) = make_uint4(q0, q1, q2, q3);
        }
    }
    __syncthreads();
    // build Toeplitz B fragments: B_c[k][j] = hpad[16c-16 + j - k], lane-ordered
    unsigned short* Bb = (unsigned short*)(smem + 18432);
    for (int e = tid; e < 34 * 64; e += 256) {
        int cc = e >> 6, ll = e & 63;
        int base = 16 * cc - 16 + (ll & 31) - 8 * (ll >> 5);
        unsigned short vals[8];
#pragma unroll
        for (int i = 0; i < 8; ++i) {
            int idx = base - i;
            vals[i] = (idx >= 0 && idx < 512) ? hs[idx] : (unsigned short)0;
        }
        unsigned int q0 = vals[0] | ((unsigned int)vals[1] << 16);
        unsigned int q1 = vals[2] | ((unsigned int)vals[3] << 16);
        unsigned int q2 = vals[4] | ((unsigned int)vals[5] << 16);
        unsigned int q3 = vals[6] | ((unsigned int)vals[7] << 16);
        *(uint4*)(Bb + e * 8) = make_uint4(q0, q1, q2, q3);
    }
    __syncthreads();

    const int w = tid >> 6, l = tid & 63;
    const int lq = 4 * (l & 31) + (l >> 5);
    const int ubase = (w << 8) + 66 + lq;               // unit idx for c=0, tile r=0
    f32x16 acc0, acc1;
#pragma unroll
    for (int i = 0; i < 16; ++i) { acc0[i] = 0.f; acc1[i] = 0.f; }
    const unsigned char* Bp = smem + 18432 + l * 16;
    for (int cc = 0; cc < 34; ++cc) {
        bf16x8 bfr = *(const bf16x8*)(Bp + cc * 1024);
        int u0 = ubase - 2 * cc;
        int u1 = u0 + 128;
        const bf16x8 a0 = *(const bf16x8*)(smem + ((u0 ^ ((u0 >> 3) & 7)) << 4));
        const bf16x8 a1 = *(const bf16x8*)(smem + ((u1 ^ ((u1 >> 3) & 7)) << 4));
        acc0 = __builtin_amdgcn_mfma_f32_32x32x16_bf16(a0, bfr, acc0, 0, 0, 0);
        acc1 = __builtin_amdgcn_mfma_f32_32x32x16_bf16(a1, bfr, acc1, 0, 0, 0);
    }
    // D layout (verified): col = l&31, row m = (r&3) + 8*(r>>2) + 4*(l>>5)
    float* yb = y + (size_t)b * 32768 + n0 + (w << 11) + (l & 31);
#pragma unroll
    for (int r = 0; r < 16; ++r) {
        int m = (r & 3) + 8 * (r >> 2) + 4 * (l >> 5);
        yb[m << 5] = acc0[r];
        yb[1024 + (m << 5)] = acc1[r];
    }
}

extern "C" void kernel_launch(void* const* d_in, const int* in_sizes, int n_in,
                              void* d_out, int out_size, void* d_ws, size_t ws_size,
                              hipStream_t stream) {
    const float* x    = (const float*)d_in[0];
    const float* c    = (const float*)d_in[1];
    const float* W0   = (const float*)d_in[2];
    const float* b0   = (const float*)d_in[3];
    const float* al   = (const float*)d_in[4];
    const float* Wg   = (const float*)d_in[5];
    const float* bg   = (const float*)d_in[6];
    const float* Wb   = (const float*)d_in[7];
    const float* bb   = (const float*)d_in[8];
    const float* Wglu = (const float*)d_in[9];
    const float* bglu = (const float*)d_in[10];
    const float* Wf   = (const float*)d_in[11];
    const float* bf   = (const float*)d_in[12];
    float* y = (float*)d_out;

    char* ws = (char*)d_ws;
    unsigned short* cfilm = (unsigned short*)(ws);             // 512 KB
    unsigned short* WgluT = (unsigned short*)(ws + 524288);    // 1 MB
    unsigned short* WfT   = (unsigned short*)(ws + 1572864);   // 512 KB
    unsigned short* cglu  = (unsigned short*)(ws + 2097152);   // 512 KB
    unsigned short* hbf   = (unsigned short*)(ws + 2621440);   // 512 KB

    k0_convert<<<dim3(3072), dim3(256), 0, stream>>>(Wglu, Wf, WgluT, WfT);
    k1_film<<<dim3(1024), dim3(256), 0, stream>>>(c, W0, b0, al, Wg, bg, Wb, bb, cfilm);
    k2_glu<<<dim3(64), dim3(256), 0, stream>>>(cfilm, WgluT, bglu, cglu);
    k3_filt<<<dim3(64), dim3(256), 0, stream>>>(cglu, WfT, bf, hbf);
    k4_conv<<<dim3(2048), dim3(256), 0, stream>>>(x, hbf, y);
}

// Round 2
// 66.044 us; speedup vs baseline: 1.1069x; 1.1069x over previous
//
#include <hip/hip_runtime.h>

// B=512 batches, MBS=32768 samples, F=512 taps, CD=16 cond dims.
// y[b,n] = sum_{t<512} h[b,t] * x[b,n-t]  (linear conv, zero history)

typedef float f32x16 __attribute__((ext_vector_type(16)));
typedef float f32x4  __attribute__((ext_vector_type(4)));
typedef __bf16 bf16x8 __attribute__((ext_vector_type(8)));

__device__ __forceinline__ unsigned short f2bf(float f) {
    unsigned int u = __float_as_uint(f);
    u += 0x7FFFu + ((u >> 16) & 1u);   // round-to-nearest-even
    return (unsigned short)(u >> 16);
}

// ---------------- kA: fused transpose(Wglu,Wf)->bf16  +  FiLM stage ----------------
// blocks [0,128): WgluT 64x64 tiles; [128,192): WfT tiles; [192,1216): k1 FiLM.
__global__ __launch_bounds__(256) void kA(
    const float* __restrict__ Wglu, const float* __restrict__ Wf,
    const float* __restrict__ c, const float* __restrict__ W0,
    const float* __restrict__ b0, const float* __restrict__ alpha,
    const float* __restrict__ Wg, const float* __restrict__ bg,
    const float* __restrict__ Wb, const float* __restrict__ bb,
    unsigned short* __restrict__ WgluT, unsigned short* __restrict__ WfT,
    unsigned short* __restrict__ cfilm) {
    const int blk = blockIdx.x, tid = threadIdx.x;
    if (blk < 192) {
        __shared__ float ldsF[64 * 65];
        const float* src; unsigned short* dst; int tj, tk, srcld, dstld;
        if (blk < 128) { tj = blk >> 3; tk = blk & 7; src = Wglu; dst = WgluT; srcld = 1024; dstld = 512; }
        else { int b2 = blk - 128; tj = b2 >> 3; tk = b2 & 7; src = Wf; dst = WfT; srcld = 512; dstld = 512; }
        // load 64x64 tile coalesced: rows = k (src-major), cols = j
#pragma unroll
        for (int rr = 0; rr < 16; ++rr) {
            int kl = (tid >> 6) + (rr << 2);
            int jl = tid & 63;
            ldsF[kl * 65 + jl] = src[(size_t)(tk * 64 + kl) * srcld + tj * 64 + jl];
        }
        __syncthreads();
        // write transposed coalesced: rows = j, cols = k
#pragma unroll
        for (int rr = 0; rr < 16; ++rr) {
            int jl = (tid >> 6) + (rr << 2);
            int kl = tid & 63;
            dst[(size_t)(tj * 64 + jl) * dstld + tk * 64 + kl] = f2bf(ldsF[kl * 65 + jl]);
        }
    } else {
        int id = (blk - 192) * 256 + tid;           // [0, 262144): b*512+f
        int b = id >> 9, f = id & 511;
        const float* cb = c + b * 16;
        float d0 = 0.f, dg = 0.f, db = 0.f;
#pragma unroll
        for (int i = 0; i < 16; ++i) {
            float cv = cb[i];
            d0 += cv * W0[i * 512 + f];
            dg += cv * Wg[i * 512 + f];
            db += cv * Wb[i * 512 + f];
        }
        float pre = d0 + b0[f];
        float pr = pre >= 0.f ? pre : alpha[f] * pre;
        float v = pr * (dg + bg[f]) + (db + bb[f]);
        cfilm[id] = f2bf(v);
    }
}

// ---------------- k2: GLU GEMM (16x16x32 MFMA), fused a*sigmoid(gate) ----------------
// 1024 waves: 32 m-tiles x 32 col-pair-tiles of 16.
__global__ __launch_bounds__(256) void k2_glu(
    const unsigned short* __restrict__ cfilm, const unsigned short* __restrict__ WgluT,
    const float* __restrict__ bglu, unsigned short* __restrict__ cglu) {
    int wid = (blockIdx.x * 256 + threadIdx.x) >> 6;    // [0,1024)
    int l = threadIdx.x & 63;
    int tm = wid >> 5, tn = wid & 31;
    int row = tm * 16 + (l & 15);
    int col = tn * 16 + (l & 15);
    int kh = 8 * (l >> 4);
    f32x4 accA, accG;
#pragma unroll
    for (int i = 0; i < 4; ++i) { accA[i] = 0.f; accG[i] = 0.f; }
    const unsigned short* ap  = cfilm + row * 512 + kh;
    const unsigned short* bap = WgluT + col * 512 + kh;
    const unsigned short* bgp = WgluT + (512 + col) * 512 + kh;
#pragma unroll
    for (int kc = 0; kc < 16; ++kc) {
        bf16x8 a   = *(const bf16x8*)(ap  + kc * 32);
        bf16x8 ba  = *(const bf16x8*)(bap + kc * 32);
        bf16x8 bgt = *(const bf16x8*)(bgp + kc * 32);
        accA = __builtin_amdgcn_mfma_f32_16x16x32_bf16(a, ba,  accA, 0, 0, 0);
        accG = __builtin_amdgcn_mfma_f32_16x16x32_bf16(a, bgt, accG, 0, 0, 0);
    }
    float biasA = bglu[col], biasG = bglu[512 + col];
#pragma unroll
    for (int r = 0; r < 4; ++r) {
        float ga = accA[r] + biasA;
        float gg = accG[r] + biasG;
        float s = 1.f / (1.f + expf(-gg));
        int m = (l >> 4) * 4 + r;                   // D: col=l&15, row=(l>>4)*4+r
        cglu[(tm * 16 + m) * 512 + col] = f2bf(ga * s);
    }
}

// ---------------- k3: Dense GEMM (16x16x32) + softsign -> filters bf16 ----------------
__global__ __launch_bounds__(256) void k3_filt(
    const unsigned short* __restrict__ cglu, const unsigned short* __restrict__ WfT,
    const float* __restrict__ bfv, unsigned short* __restrict__ hout) {
    int wid = (blockIdx.x * 256 + threadIdx.x) >> 6;    // [0,1024)
    int l = threadIdx.x & 63;
    int tm = wid >> 5, tn = wid & 31;
    int row = tm * 16 + (l & 15);
    int col = tn * 16 + (l & 15);
    int kh = 8 * (l >> 4);
    f32x4 acc;
#pragma unroll
    for (int i = 0; i < 4; ++i) acc[i] = 0.f;
    const unsigned short* ap = cglu + row * 512 + kh;
    const unsigned short* bp = WfT + col * 512 + kh;
#pragma unroll
    for (int kc = 0; kc < 16; ++kc) {
        bf16x8 a  = *(const bf16x8*)(ap + kc * 32);
        bf16x8 bv = *(const bf16x8*)(bp + kc * 32);
        acc = __builtin_amdgcn_mfma_f32_16x16x32_bf16(a, bv, acc, 0, 0, 0);
    }
    float bias = bfv[col];
#pragma unroll
    for (int r = 0; r < 4; ++r) {
        float z = acc[r] + bias;
        float h = z / (1.f + fabsf(z));
        int m = (l >> 4) * 4 + r;
        hout[(tm * 16 + m) * 512 + col] = f2bf(h);
    }
}

// ---------------- kB: per-batch Toeplitz B-fragment table -> global ----------------
// Bfrag[b][cc][lane][8]: B_c[k][j] = h[16c-16 + j - k], lane-ordered for MFMA B-operand.
__global__ __launch_bounds__(256) void kB_frag(
    const unsigned short* __restrict__ hbf, unsigned short* __restrict__ Bfrag) {
    __shared__ unsigned short hs[512];
    const int b = blockIdx.x, tid = threadIdx.x;
    ((unsigned int*)hs)[tid] = ((const unsigned int*)(hbf + (size_t)b * 512))[tid];
    __syncthreads();
    for (int e = tid; e < 34 * 64; e += 256) {
        int cc = e >> 6, ll = e & 63;
        int base = 16 * cc - 16 + (ll & 31) - 8 * (ll >> 5);
        unsigned short vals[8];
#pragma unroll
        for (int i = 0; i < 8; ++i) {
            int idx = base - i;
            vals[i] = (idx >= 0 && idx < 512) ? hs[idx] : (unsigned short)0;
        }
        unsigned int q0 = vals[0] | ((unsigned int)vals[1] << 16);
        unsigned int q1 = vals[2] | ((unsigned int)vals[3] << 16);
        unsigned int q2 = vals[4] | ((unsigned int)vals[5] << 16);
        unsigned int q3 = vals[6] | ((unsigned int)vals[7] << 16);
        *(uint4*)(Bfrag + (size_t)b * 17408 + e * 8) = make_uint4(q0, q1, q2, q3);
    }
}

// ---------------- k4g: MFMA FIR conv, x-tile-only LDS, B from global (L2) ----------------
// Block: 1 batch x 8192 outputs. 4 waves x 2 tiles(1024 outs). LDS 17408 B.
__global__ __launch_bounds__(256, 6) void k4g(
    const float* __restrict__ x, const unsigned short* __restrict__ Bfrag,
    float* __restrict__ y) {
    __shared__ __align__(16) unsigned char smem[17408];
    const int tid = threadIdx.x;
    const int b = blockIdx.x >> 2;
    const int n0 = (blockIdx.x & 3) << 13;
    const float* xb = x + (size_t)b * 32768;
#pragma unroll
    for (int it = 0; it < 5; ++it) {
        int u = tid + (it << 8);
        if (u < 1088) {
            int g0 = n0 - 512 + (u << 3);
            unsigned short us[8];
            if (g0 >= 0) {
                const float4* p = (const float4*)(xb + g0);
                float4 v0 = p[0], v1 = p[1];
                us[0] = f2bf(v0.x); us[1] = f2bf(v0.y); us[2] = f2bf(v0.z); us[3] = f2bf(v0.w);
                us[4] = f2bf(v1.x); us[5] = f2bf(v1.y); us[6] = f2bf(v1.z); us[7] = f2bf(v1.w);
            } else {
#pragma unroll
                for (int i = 0; i < 8; ++i) us[i] = 0;
            }
            int su = u ^ ((u >> 3) & 7);
            unsigned int q0 = us[0] | ((unsigned int)us[1] << 16);
            unsigned int q1 = us[2] | ((unsigned int)us[3] << 16);
            unsigned int q2 = us[4] | ((unsigned int)us[5] << 16);
            unsigned int q3 = us[6] | ((unsigned int)us[7] << 16);
            *(uint4*)(smem + (su << 4)) = make_uint4(q0, q1, q2, q3);
        }
    }
    __syncthreads();

    const int w = tid >> 6, l = tid & 63;
    const int lq = 4 * (l & 31) + (l >> 5);
    const int ubase = (w << 8) + 66 + lq;
    f32x16 acc0, acc1;
#pragma unroll
    for (int i = 0; i < 16; ++i) { acc0[i] = 0.f; acc1[i] = 0.f; }
    const unsigned short* Bp = Bfrag + (size_t)b * 17408 + l * 8;
    bf16x8 bnext = *(const bf16x8*)(Bp);                 // prefetch cc=0
    for (int cc = 0; cc < 34; ++cc) {
        bf16x8 bfr = bnext;
        if (cc < 33) bnext = *(const bf16x8*)(Bp + (cc + 1) * 512);
        int u0 = ubase - 2 * cc;
        int u1 = u0 + 128;
        const bf16x8 a0 = *(const bf16x8*)(smem + ((u0 ^ ((u0 >> 3) & 7)) << 4));
        const bf16x8 a1 = *(const bf16x8*)(smem + ((u1 ^ ((u1 >> 3) & 7)) << 4));
        acc0 = __builtin_amdgcn_mfma_f32_32x32x16_bf16(a0, bfr, acc0, 0, 0, 0);
        acc1 = __builtin_amdgcn_mfma_f32_32x32x16_bf16(a1, bfr, acc1, 0, 0, 0);
    }
    float* yb = y + (size_t)b * 32768 + n0 + (w << 11) + (l & 31);
#pragma unroll
    for (int r = 0; r < 16; ++r) {
        int m = (r & 3) + 8 * (r >> 2) + 4 * (l >> 5);   // D: col=l&31, row m
        yb[m << 5] = acc0[r];
        yb[1024 + (m << 5)] = acc1[r];
    }
}

// ---------------- k4 fallback: in-LDS B build (R0 version, proven) ----------------
__global__ __launch_bounds__(256) void k4_conv(
    const float* __restrict__ x, const unsigned short* __restrict__ hbf,
    float* __restrict__ y) {
    __shared__ __align__(16) unsigned char smem[53248];
    const int tid = threadIdx.x;
    const int b = blockIdx.x >> 2;
    const int n0 = (blockIdx.x & 3) << 13;
    unsigned short* hs = (unsigned short*)(smem + 17408);
    ((unsigned int*)hs)[tid] = ((const unsigned int*)(hbf + (size_t)b * 512))[tid];
    const float* xb = x + (size_t)b * 32768;
#pragma unroll
    for (int it = 0; it < 5; ++it) {
        int u = tid + (it << 8);
        if (u < 1088) {
            int g0 = n0 - 512 + (u << 3);
            unsigned short us[8];
            if (g0 >= 0) {
                const float4* p = (const float4*)(xb + g0);
                float4 v0 = p[0], v1 = p[1];
                us[0] = f2bf(v0.x); us[1] = f2bf(v0.y); us[2] = f2bf(v0.z); us[3] = f2bf(v0.w);
                us[4] = f2bf(v1.x); us[5] = f2bf(v1.y); us[6] = f2bf(v1.z); us[7] = f2bf(v1.w);
            } else {
#pragma unroll
                for (int i = 0; i < 8; ++i) us[i] = 0;
            }
            int su = u ^ ((u >> 3) & 7);
            unsigned int q0 = us[0] | ((unsigned int)us[1] << 16);
            unsigned int q1 = us[2] | ((unsigned int)us[3] << 16);
            unsigned int q2 = us[4] | ((unsigned int)us[5] << 16);
            unsigned int q3 = us[6] | ((unsigned int)us[7] << 16);
            *(uint4*)(smem + (su << 4)) = make_uint4(q0, q1, q2, q3);
        }
    }
    __syncthreads();
    unsigned short* Bb = (unsigned short*)(smem + 18432);
    for (int e = tid; e < 34 * 64; e += 256) {
        int cc = e >> 6, ll = e & 63;
        int base = 16 * cc - 16 + (ll & 31) - 8 * (ll >> 5);
        unsigned short vals[8];
#pragma unroll
        for (int i = 0; i < 8; ++i) {
            int idx = base - i;
            vals[i] = (idx >= 0 && idx < 512) ? hs[idx] : (unsigned short)0;
        }
        unsigned int q0 = vals[0] | ((unsigned int)vals[1] << 16);
        unsigned int q1 = vals[2] | ((unsigned int)vals[3] << 16);
        unsigned int q2 = vals[4] | ((unsigned int)vals[5] << 16);
        unsigned int q3 = vals[6] | ((unsigned int)vals[7] << 16);
        *(uint4*)(Bb + e * 8) = make_uint4(q0, q1, q2, q3);
    }
    __syncthreads();
    const int w = tid >> 6, l = tid & 63;
    const int lq = 4 * (l & 31) + (l >> 5);
    const int ubase = (w << 8) + 66 + lq;
    f32x16 acc0, acc1;
#pragma unroll
    for (int i = 0; i < 16; ++i) { acc0[i] = 0.f; acc1[i] = 0.f; }
    const unsigned char* Bp = smem + 18432 + l * 16;
    for (int cc = 0; cc < 34; ++cc) {
        bf16x8 bfr = *(const bf16x8*)(Bp + cc * 1024);
        int u0 = ubase - 2 * cc;
        int u1 = u0 + 128;
        const bf16x8 a0 = *(const bf16x8*)(smem + ((u0 ^ ((u0 >> 3) & 7)) << 4));
        const bf16x8 a1 = *(const bf16x8*)(smem + ((u1 ^ ((u1 >> 3) & 7)) << 4));
        acc0 = __builtin_amdgcn_mfma_f32_32x32x16_bf16(a0, bfr, acc0, 0, 0, 0);
        acc1 = __builtin_amdgcn_mfma_f32_32x32x16_bf16(a1, bfr, acc1, 0, 0, 0);
    }
    float* yb = y + (size_t)b * 32768 + n0 + (w << 11) + (l & 31);
#pragma unroll
    for (int r = 0; r < 16; ++r) {
        int m = (r & 3) + 8 * (r >> 2) + 4 * (l >> 5);
        yb[m << 5] = acc0[r];
        yb[1024 + (m << 5)] = acc1[r];
    }
}

extern "C" void kernel_launch(void* const* d_in, const int* in_sizes, int n_in,
                              void* d_out, int out_size, void* d_ws, size_t ws_size,
                              hipStream_t stream) {
    const float* x    = (const float*)d_in[0];
    const float* c    = (const float*)d_in[1];
    const float* W0   = (const float*)d_in[2];
    const float* b0   = (const float*)d_in[3];
    const float* al   = (const float*)d_in[4];
    const float* Wg   = (const float*)d_in[5];
    const float* bg   = (const float*)d_in[6];
    const float* Wb   = (const float*)d_in[7];
    const float* bb   = (const float*)d_in[8];
    const float* Wglu = (const float*)d_in[9];
    const float* bglu = (const float*)d_in[10];
    const float* Wf   = (const float*)d_in[11];
    const float* bf   = (const float*)d_in[12];
    float* y = (float*)d_out;

    char* ws = (char*)d_ws;
    unsigned short* cfilm = (unsigned short*)(ws);             // 512 KB
    unsigned short* WgluT = (unsigned short*)(ws + 524288);    // 1 MB
    unsigned short* WfT   = (unsigned short*)(ws + 1572864);   // 512 KB
    unsigned short* cglu  = (unsigned short*)(ws + 2097152);   // 512 KB
    unsigned short* hbf   = (unsigned short*)(ws + 2621440);   // 512 KB
    unsigned short* Bfrag = (unsigned short*)(ws + 3145728);   // 17.8 MB

    kA<<<dim3(1216), dim3(256), 0, stream>>>(Wglu, Wf, c, W0, b0, al, Wg, bg, Wb, bb,
                                             WgluT, WfT, cfilm);
    k2_glu<<<dim3(256), dim3(256), 0, stream>>>(cfilm, WgluT, bglu, cglu);
    k3_filt<<<dim3(256), dim3(256), 0, stream>>>(cglu, WfT, bf, hbf);
    if (ws_size >= (size_t)(3145728 + 512 * 34816)) {
        kB_frag<<<dim3(512), dim3(256), 0, stream>>>(hbf, Bfrag);
        k4g<<<dim3(2048), dim3(256), 0, stream>>>(x, Bfrag, y);
    } else {
        k4_conv<<<dim3(2048), dim3(256), 0, stream>>>(x, hbf, y);
    }
}